// Round 4
// baseline (177.074 us; speedup 1.0000x reference)
//
#include <hip/hip_runtime.h>
#include <hip/hip_bf16.h>

// CrossViewAttention: B=4, V=6, C=256, H=W=64 (HW=4096), heads=8, dh=32.
//
// Pipeline (6 launches):
//   1. convert_weights: Wq/Wk/Wv/Wo fp32 -> bf16
//   2. transpose_mean:  x[b][v][c][w] -> xt[b][v][w][c] bf16, xbar[b][w][c] bf16 (mean over v)
//   3. gemm: Qloc[b][w][c] bf16 = xbar @ Wq^T     ([w][c] layout)
//   4. fused gemm: Kt = xt @ Wk^T AND Vt = xt @ Wv^T in one pass (A staged once)
//   5. attn: one thread per (b,w,h) — contiguous 64B loads per head
//   6. gemm: d_out[b][o][w] fp32 = Wo @ attnT

typedef __bf16 bf16x8 __attribute__((ext_vector_type(8)));
typedef float f32x4 __attribute__((ext_vector_type(4)));

#define HW 4096
#define C_DIM 256
#define NV 6
#define NB 4

__global__ __launch_bounds__(256) void convert_weights_kernel(
    const float* __restrict__ Wq, const float* __restrict__ Wk,
    const float* __restrict__ Wv, const float* __restrict__ Wo,
    __hip_bfloat16* __restrict__ out)
{
    const float* srcs[4] = {Wq, Wk, Wv, Wo};
    const int m = blockIdx.y;
    const int i = blockIdx.x * 256 + threadIdx.x;
    out[m * 65536 + i] = __float2bfloat16(srcs[m][i]);
}

// 64x64 tile transpose via LDS; accumulates per-view sum for xbar.
__global__ __launch_bounds__(256) void transpose_mean_kernel(
    const float* __restrict__ x,        // [B][V][C][HW]
    __hip_bfloat16* __restrict__ xt,    // [B][V][HW][C]
    __hip_bfloat16* __restrict__ xbar)  // [B][HW][C]
{
    __shared__ float tile[64][65];
    const int w0 = blockIdx.x * 64;
    const int c0 = blockIdx.y * 64;
    const int b  = blockIdx.z;
    const int t  = threadIdx.x;
    const int li = t & 63;
    const int qi = t >> 6;
    float acc[16];
#pragma unroll
    for (int i = 0; i < 16; ++i) acc[i] = 0.f;

    for (int v = 0; v < NV; ++v) {
        const float* src = x + (((size_t)b * NV + v) * C_DIM + c0) * HW + w0;
#pragma unroll
        for (int i = 0; i < 16; ++i) {
            const int c = qi + 4 * i;
            tile[li][c] = src[(size_t)c * HW + li];
        }
        __syncthreads();
        __hip_bfloat16* dst = xt + (((size_t)b * NV + v) * HW + w0) * C_DIM + c0;
#pragma unroll
        for (int i = 0; i < 16; ++i) {
            const int w = qi + 4 * i;
            const float val = tile[w][li];
            acc[i] += val;
            dst[(size_t)w * C_DIM + li] = __float2bfloat16(val);
        }
        __syncthreads();
    }
    __hip_bfloat16* dbar = xbar + ((size_t)b * HW + w0) * C_DIM + c0;
#pragma unroll
    for (int i = 0; i < 16; ++i) {
        const int w = qi + 4 * i;
        dbar[(size_t)w * C_DIM + li] = __float2bfloat16(acc[i] * (1.f / 6.f));
    }
}

// Generic 128x128-tile GEMM, K=256:  C[z][row][col] = A_z[row][k] * B_z[col][k]
template<int OUT_BF16>
__global__ __launch_bounds__(256) void gemm_generic(
    const __hip_bfloat16* __restrict__ Abase, size_t strideA,
    const __hip_bfloat16* __restrict__ Bbase, size_t strideB,
    void* __restrict__ Cv, size_t strideC, int ldc)
{
    __shared__ __align__(16) __hip_bfloat16 Alds[4096];  // [kb 0..3][row 0..127][8]
    __shared__ __align__(16) __hip_bfloat16 Blds[4096];
    const int n0 = blockIdx.x * 128;
    const int m0 = blockIdx.y * 128;
    const int z  = blockIdx.z;
    const __hip_bfloat16* A = Abase + (size_t)z * strideA;
    const __hip_bfloat16* B = Bbase + (size_t)z * strideB;

    const int t  = threadIdx.x;
    const int wv = t >> 6, l = t & 63;
    const int wr = wv >> 1, wc = wv & 1;

    f32x4 acc[4][4];
#pragma unroll
    for (int i = 0; i < 4; ++i)
#pragma unroll
        for (int j = 0; j < 4; ++j) {
            acc[i][j][0] = 0.f; acc[i][j][1] = 0.f;
            acc[i][j][2] = 0.f; acc[i][j][3] = 0.f;
        }

    const int matB = wv >> 1;
    const __hip_bfloat16* gsrc = matB ? B : A;
    __hip_bfloat16* lbase = matB ? Blds : Alds;
    const int rbase = matB ? n0 : m0;

    const int kb_l = l >> 4;
    const int rl   = l & 15;

    for (int k0 = 0; k0 < 256; k0 += 32) {
#pragma unroll
        for (int c2 = 0; c2 < 4; ++c2) {
            const int c    = (wv & 1) * 4 + c2;   // 0..7 across the two waves
            const int kb   = c >> 1, half = c & 1;
            const int row  = half * 64 + l;
            const __hip_bfloat16* g = gsrc + (size_t)(rbase + row) * 256 + (k0 + kb * 8);
            __builtin_amdgcn_global_load_lds(
                (const __attribute__((address_space(1))) void*)g,
                (__attribute__((address_space(3))) void*)(lbase + kb * 1024 + half * 512),
                16, 0, 0);
        }
        __syncthreads();

        bf16x8 af[4], bfr[4];
#pragma unroll
        for (int i = 0; i < 4; ++i)
            af[i] = *(const bf16x8*)&Alds[kb_l * 1024 + (wr * 64 + i * 16 + rl) * 8];
#pragma unroll
        for (int j = 0; j < 4; ++j)
            bfr[j] = *(const bf16x8*)&Blds[kb_l * 1024 + (wc * 64 + j * 16 + rl) * 8];
#pragma unroll
        for (int i = 0; i < 4; ++i)
#pragma unroll
            for (int j = 0; j < 4; ++j)
                acc[i][j] = __builtin_amdgcn_mfma_f32_16x16x32_bf16(af[i], bfr[j], acc[i][j], 0, 0, 0);
        __syncthreads();
    }

    const int r0 = (l >> 4) * 4;
    const int cl = l & 15;
#pragma unroll
    for (int i = 0; i < 4; ++i) {
        const int row = m0 + wr * 64 + i * 16 + r0;
#pragma unroll
        for (int j = 0; j < 4; ++j) {
            const int col = n0 + wc * 64 + j * 16 + cl;
            if (OUT_BF16) {
                __hip_bfloat16* Cp = (__hip_bfloat16*)Cv + (size_t)z * strideC;
#pragma unroll
                for (int r = 0; r < 4; ++r)
                    Cp[(size_t)(row + r) * ldc + col] = __float2bfloat16(acc[i][j][r]);
            } else {
                float* Cp = (float*)Cv + (size_t)z * strideC;
#pragma unroll
                for (int r = 0; r < 4; ++r)
                    Cp[(size_t)(row + r) * ldc + col] = acc[i][j][r];
            }
        }
    }
}

// Fused K/V GEMM: one A-tile (xt pixels) staged once, two B operands (Wk, Wv),
// two accumulator sets, 32 MFMA per K-step. Outputs bf16 [z][w][c].
// Staging: 3 buffers x 8 chunks (4 kb x 2 halves) of 1KB = 24 chunks, 6 per wave.
__global__ __launch_bounds__(256) void gemm_kv_kernel(
    const __hip_bfloat16* __restrict__ xt,   // [z][4096][256]
    const __hip_bfloat16* __restrict__ Wk,   // [256][256]
    const __hip_bfloat16* __restrict__ Wv,   // [256][256]
    __hip_bfloat16* __restrict__ Kt,         // [z][4096][256]
    __hip_bfloat16* __restrict__ Vt)         // [z][4096][256]
{
    __shared__ __align__(16) __hip_bfloat16 Alds[4096];   // [kb][row 0..127][8]
    __shared__ __align__(16) __hip_bfloat16 Bklds[4096];
    __shared__ __align__(16) __hip_bfloat16 Bvlds[4096];
    const int n0 = blockIdx.x * 128;
    const int m0 = blockIdx.y * 128;
    const int z  = blockIdx.z;
    const __hip_bfloat16* A = xt + (size_t)z * (HW * C_DIM);

    const int t  = threadIdx.x;
    const int wv = t >> 6, l = t & 63;
    const int wr = wv >> 1, wc = wv & 1;

    f32x4 acck[4][4], accv[4][4];
#pragma unroll
    for (int i = 0; i < 4; ++i)
#pragma unroll
        for (int j = 0; j < 4; ++j) {
#pragma unroll
            for (int r = 0; r < 4; ++r) { acck[i][j][r] = 0.f; accv[i][j][r] = 0.f; }
        }

    const int kb_l = l >> 4;
    const int rl   = l & 15;

    for (int k0 = 0; k0 < 256; k0 += 32) {
        // 24 staging chunks (A x8, Bk x8, Bv x8), 6 per wave
#pragma unroll
        for (int c2 = 0; c2 < 6; ++c2) {
            const int c      = wv * 6 + c2;       // 0..23
            const int target = c >> 3;            // 0:A 1:Bk 2:Bv
            const int sub    = c & 7;             // 0..7
            const int kb     = sub >> 1, half = sub & 1;
            const int row    = half * 64 + l;
            const __hip_bfloat16* gsrc =
                target == 0 ? (A + (size_t)(m0 + row) * 256)
                            : (target == 1 ? (Wk + (size_t)(n0 + row) * 256)
                                           : (Wv + (size_t)(n0 + row) * 256));
            __hip_bfloat16* lbase = target == 0 ? Alds : (target == 1 ? Bklds : Bvlds);
            __builtin_amdgcn_global_load_lds(
                (const __attribute__((address_space(1))) void*)(gsrc + k0 + kb * 8),
                (__attribute__((address_space(3))) void*)(lbase + kb * 1024 + half * 512),
                16, 0, 0);
        }
        __syncthreads();

        bf16x8 af[4], bk[4], bv[4];
#pragma unroll
        for (int i = 0; i < 4; ++i)
            af[i] = *(const bf16x8*)&Alds[kb_l * 1024 + (wr * 64 + i * 16 + rl) * 8];
#pragma unroll
        for (int j = 0; j < 4; ++j) {
            bk[j] = *(const bf16x8*)&Bklds[kb_l * 1024 + (wc * 64 + j * 16 + rl) * 8];
            bv[j] = *(const bf16x8*)&Bvlds[kb_l * 1024 + (wc * 64 + j * 16 + rl) * 8];
        }
#pragma unroll
        for (int i = 0; i < 4; ++i)
#pragma unroll
            for (int j = 0; j < 4; ++j) {
                acck[i][j] = __builtin_amdgcn_mfma_f32_16x16x32_bf16(af[i], bk[j], acck[i][j], 0, 0, 0);
                accv[i][j] = __builtin_amdgcn_mfma_f32_16x16x32_bf16(af[i], bv[j], accv[i][j], 0, 0, 0);
            }
        __syncthreads();
    }

    const int r0 = (l >> 4) * 4;
    const int cl = l & 15;
    __hip_bfloat16* Kp = Kt + (size_t)z * (HW * C_DIM);
    __hip_bfloat16* Vp = Vt + (size_t)z * (HW * C_DIM);
#pragma unroll
    for (int i = 0; i < 4; ++i) {
        const int row = m0 + wr * 64 + i * 16 + r0;
#pragma unroll
        for (int j = 0; j < 4; ++j) {
            const int col = n0 + wc * 64 + j * 16 + cl;
#pragma unroll
            for (int r = 0; r < 4; ++r) {
                Kp[(size_t)(row + r) * 256 + col] = __float2bfloat16(acck[i][j][r]);
                Vp[(size_t)(row + r) * 256 + col] = __float2bfloat16(accv[i][j][r]);
            }
        }
    }
}

// One thread per (b, w, h): all loads contiguous 64B per head slice.
__global__ __launch_bounds__(256) void attn_kernel(
    const __hip_bfloat16* __restrict__ Qloc,  // [nb][4096][256] bf16
    const __hip_bfloat16* __restrict__ Kt,    // [nb*6][4096][256]
    const __hip_bfloat16* __restrict__ Vt,
    __hip_bfloat16* __restrict__ outT)        // [nb][4096][256]
{
    const int t  = blockIdx.x * 256 + threadIdx.x;
    const int h  = t & 7;
    const int bw = t >> 3;                 // b*4096 + w
    const int b  = bw >> 12;
    const int w  = bw & 4095;
    const float scale = 0.17677669529663687f;  // 32^-0.5

    float q[32];
    const bf16x8* Qp = (const bf16x8*)(Qloc + (size_t)bw * C_DIM + h * 32);
#pragma unroll
    for (int i = 0; i < 4; ++i) {
        bf16x8 qv = Qp[i];
#pragma unroll
        for (int j = 0; j < 8; ++j) q[8 * i + j] = (float)qv[j];
    }

    float s[NV];
#pragma unroll
    for (int v = 0; v < NV; ++v) {
        const bf16x8* Kp = (const bf16x8*)(Kt + ((size_t)(b * NV + v) * HW + w) * C_DIM + h * 32);
        float a = 0.f;
#pragma unroll
        for (int i = 0; i < 4; ++i) {
            bf16x8 kv = Kp[i];
#pragma unroll
            for (int j = 0; j < 8; ++j) a += q[8 * i + j] * (float)kv[j];
        }
        s[v] = a * scale;
    }
    float m = s[0];
#pragma unroll
    for (int v = 1; v < NV; ++v) m = fmaxf(m, s[v]);
    float den = 0.f;
#pragma unroll
    for (int v = 0; v < NV; ++v) { s[v] = __expf(s[v] - m); den += s[v]; }
    const float inv = 1.f / den;

    float o[32];
#pragma unroll
    for (int d = 0; d < 32; ++d) o[d] = 0.f;
#pragma unroll
    for (int v = 0; v < NV; ++v) {
        const float p = s[v] * inv;
        const bf16x8* Vp = (const bf16x8*)(Vt + ((size_t)(b * NV + v) * HW + w) * C_DIM + h * 32);
#pragma unroll
        for (int i = 0; i < 4; ++i) {
            bf16x8 vv = Vp[i];
#pragma unroll
            for (int j = 0; j < 8; ++j) o[8 * i + j] += p * (float)vv[j];
        }
    }
    __hip_bfloat16* op = outT + (size_t)bw * C_DIM + h * 32;
#pragma unroll
    for (int i = 0; i < 4; ++i) {
        bf16x8 ov;
#pragma unroll
        for (int j = 0; j < 8; ++j) ov[j] = (__bf16)o[8 * i + j];
        *(bf16x8*)(op + 8 * i) = ov;
    }
}

extern "C" void kernel_launch(void* const* d_in, const int* in_sizes, int n_in,
                              void* d_out, int out_size, void* d_ws, size_t ws_size,
                              hipStream_t stream)
{
    const float* x  = (const float*)d_in[0];
    const float* Wq = (const float*)d_in[1];
    const float* Wk = (const float*)d_in[2];
    const float* Wv = (const float*)d_in[3];
    const float* Wo = (const float*)d_in[4];
    (void)in_sizes; (void)n_in; (void)out_size; (void)ws_size;

    char* ws = (char*)d_ws;
    const size_t MB = 1024ull * 1024ull;
    const size_t SL = (size_t)HW * C_DIM;                    // 1M elements per slice

    __hip_bfloat16* Wbf   = (__hip_bfloat16*)(ws);           // 512 KB
    __hip_bfloat16* xt    = (__hip_bfloat16*)(ws + 1 * MB);  // 48 MB [4*6][4096][256]
    __hip_bfloat16* Qloc  = (__hip_bfloat16*)(ws + 49 * MB); // 8 MB  [4][4096][256] bf16
    __hip_bfloat16* xbar  = (__hip_bfloat16*)(ws + 57 * MB); // 8 MB  [4][4096][256]
    __hip_bfloat16* attnT = xbar;                            // overlay: xbar dead after Qloc gemm
    __hip_bfloat16* Kt    = (__hip_bfloat16*)(ws + 65 * MB); // 48 MB
    __hip_bfloat16* Vt    = (__hip_bfloat16*)(ws + 113 * MB);// 48 MB

    const __hip_bfloat16* WqB = Wbf;
    const __hip_bfloat16* WkB = Wbf + 65536;
    const __hip_bfloat16* WvB = Wbf + 131072;
    const __hip_bfloat16* WoB = Wbf + 196608;

    convert_weights_kernel<<<dim3(256, 4), 256, 0, stream>>>(Wq, Wk, Wv, Wo, Wbf);
    transpose_mean_kernel<<<dim3(HW / 64, C_DIM / 64, NB), 256, 0, stream>>>(x, xt, xbar);

    // Qloc[b][w][c] bf16 = xbar @ Wq^T
    gemm_generic<1><<<dim3(2, 32, NB), 256, 0, stream>>>(xbar, SL, WqB, 0, Qloc, SL, 256);

    // Kt/Vt fused
    gemm_kv_kernel<<<dim3(2, 32, NB * NV), 256, 0, stream>>>(xt, WkB, WvB, Kt, Vt);

    attn_kernel<<<dim3(NB * 128), 256, 0, stream>>>(Qloc, Kt, Vt, attnT);

    // d_out[b][o][w] fp32 = Wo @ attnT
    gemm_generic<0><<<dim3(32, 2, NB), 256, 0, stream>>>(WoB, 0, attnT, SL, (float*)d_out, SL, 4096);
}

// Round 5
// 149.013 us; speedup vs baseline: 1.1883x; 1.1883x over previous
//
#include <hip/hip_runtime.h>
#include <hip/hip_bf16.h>

// CrossViewAttention: B=4, V=6, C=256, H=W=64 (HW=4096), heads=8, dh=32.
//
// Pipeline (6 launches):
//   1. convert_weights: Wq/Wk/Wv/Wo fp32 -> bf16
//   2. transpose_mean:  x[b][v][c][w] -> xt[b][v][w][c] bf16, xbar[b][w][c] bf16 (mean over v)
//   3. gemm: Qloc[b][w][c] bf16 = xbar @ Wq^T     ([w][c] layout)
//   4. fused gemm: Kt = xt @ Wk^T AND Vt = xt @ Wv^T in one pass (A staged once)
//   5. attn: one thread per (b,w,h) — contiguous 64B loads per head
//   6. gemm: d_out[b][o][w] fp32 = Wo @ attnT
//
// GEMMs use 2-phase double-buffered staging with counted vmcnt (T3+T4 minimal):
// next K-step's global_load_lds stays in flight across the barrier; each step
// waits only for its own buffer (vmcnt(N), never 0 in steady state).

typedef __bf16 bf16x8 __attribute__((ext_vector_type(8)));
typedef float f32x4 __attribute__((ext_vector_type(4)));

#define HW 4096
#define C_DIM 256
#define NV 6
#define NB 4

__global__ __launch_bounds__(256) void convert_weights_kernel(
    const float* __restrict__ Wq, const float* __restrict__ Wk,
    const float* __restrict__ Wv, const float* __restrict__ Wo,
    __hip_bfloat16* __restrict__ out)
{
    const float* srcs[4] = {Wq, Wk, Wv, Wo};
    const int m = blockIdx.y;
    const int i = blockIdx.x * 256 + threadIdx.x;
    out[m * 65536 + i] = __float2bfloat16(srcs[m][i]);
}

// 64x64 tile transpose via LDS; accumulates per-view sum for xbar.
__global__ __launch_bounds__(256) void transpose_mean_kernel(
    const float* __restrict__ x,        // [B][V][C][HW]
    __hip_bfloat16* __restrict__ xt,    // [B][V][HW][C]
    __hip_bfloat16* __restrict__ xbar)  // [B][HW][C]
{
    __shared__ float tile[64][65];
    const int w0 = blockIdx.x * 64;
    const int c0 = blockIdx.y * 64;
    const int b  = blockIdx.z;
    const int t  = threadIdx.x;
    const int li = t & 63;
    const int qi = t >> 6;
    float acc[16];
#pragma unroll
    for (int i = 0; i < 16; ++i) acc[i] = 0.f;

    for (int v = 0; v < NV; ++v) {
        const float* src = x + (((size_t)b * NV + v) * C_DIM + c0) * HW + w0;
#pragma unroll
        for (int i = 0; i < 16; ++i) {
            const int c = qi + 4 * i;
            tile[li][c] = src[(size_t)c * HW + li];
        }
        __syncthreads();
        __hip_bfloat16* dst = xt + (((size_t)b * NV + v) * HW + w0) * C_DIM + c0;
#pragma unroll
        for (int i = 0; i < 16; ++i) {
            const int w = qi + 4 * i;
            const float val = tile[w][li];
            acc[i] += val;
            dst[(size_t)w * C_DIM + li] = __float2bfloat16(val);
        }
        __syncthreads();
    }
    __hip_bfloat16* dbar = xbar + ((size_t)b * HW + w0) * C_DIM + c0;
#pragma unroll
    for (int i = 0; i < 16; ++i) {
        const int w = qi + 4 * i;
        dbar[(size_t)w * C_DIM + li] = __float2bfloat16(acc[i] * (1.f / 6.f));
    }
}

// Generic 128x128-tile GEMM, K=256:  C[z][row][col] = A_z[row][k] * B_z[col][k]
// 2-phase dbuf: stage(kt+2) issued after the read-done barrier; steady-state
// wait is vmcnt(4) = skip the newer stage's 4 in-flight loads.
template<int OUT_BF16>
__global__ __launch_bounds__(256) void gemm_generic(
    const __hip_bfloat16* __restrict__ Abase, size_t strideA,
    const __hip_bfloat16* __restrict__ Bbase, size_t strideB,
    void* __restrict__ Cv, size_t strideC, int ldc)
{
    __shared__ __align__(16) __hip_bfloat16 Alds[2][4096];  // [buf][kb 0..3][row 0..127][8]
    __shared__ __align__(16) __hip_bfloat16 Blds[2][4096];
    const int n0 = blockIdx.x * 128;
    const int m0 = blockIdx.y * 128;
    const int z  = blockIdx.z;
    const __hip_bfloat16* A = Abase + (size_t)z * strideA;
    const __hip_bfloat16* B = Bbase + (size_t)z * strideB;

    const int t  = threadIdx.x;
    const int wv = t >> 6, l = t & 63;
    const int wr = wv >> 1, wc = wv & 1;

    f32x4 acc[4][4];
#pragma unroll
    for (int i = 0; i < 4; ++i)
#pragma unroll
        for (int j = 0; j < 4; ++j) {
            acc[i][j][0] = 0.f; acc[i][j][1] = 0.f;
            acc[i][j][2] = 0.f; acc[i][j][3] = 0.f;
        }

    const int matB = wv >> 1;
    const __hip_bfloat16* gsrc = matB ? B : A;
    __hip_bfloat16* lds0 = matB ? &Blds[0][0] : &Alds[0][0];
    const int rbase = matB ? n0 : m0;

    const int kb_l = l >> 4;
    const int rl   = l & 15;

    // stage one K-step (32 k) into buffer `buf`: 8 chunks of 1KB, 4 per wave
    auto stage = [&](int buf, int k0) {
#pragma unroll
        for (int c2 = 0; c2 < 4; ++c2) {
            const int c    = (wv & 1) * 4 + c2;   // 0..7 across the two waves
            const int kb   = c >> 1, half = c & 1;
            const int row  = half * 64 + l;
            const __hip_bfloat16* g = gsrc + (size_t)(rbase + row) * 256 + (k0 + kb * 8);
            __builtin_amdgcn_global_load_lds(
                (const __attribute__((address_space(1))) void*)g,
                (__attribute__((address_space(3))) void*)(lds0 + buf * 4096 + kb * 1024 + half * 512),
                16, 0, 0);
        }
    };

    stage(0, 0);
    stage(1, 32);

    for (int kt = 0; kt < 8; ++kt) {
        const int buf = kt & 1;
        // wait for this buffer's loads only; the newer stage (4 loads) stays in flight
        if (kt < 7) asm volatile("s_waitcnt vmcnt(4)" ::: "memory");
        else        asm volatile("s_waitcnt vmcnt(0)" ::: "memory");
        __builtin_amdgcn_s_barrier();          // every wave has waited -> buf complete
        asm volatile("" ::: "memory");

        bf16x8 af[4], bfr[4];
#pragma unroll
        for (int i = 0; i < 4; ++i)
            af[i] = *(const bf16x8*)&Alds[buf][kb_l * 1024 + (wr * 64 + i * 16 + rl) * 8];
#pragma unroll
        for (int j = 0; j < 4; ++j)
            bfr[j] = *(const bf16x8*)&Blds[buf][kb_l * 1024 + (wc * 64 + j * 16 + rl) * 8];
#pragma unroll
        for (int i = 0; i < 4; ++i)
#pragma unroll
            for (int j = 0; j < 4; ++j)
                acc[i][j] = __builtin_amdgcn_mfma_f32_16x16x32_bf16(af[i], bfr[j], acc[i][j], 0, 0, 0);

        asm volatile("" ::: "memory");
        __builtin_amdgcn_s_barrier();          // all waves done reading buf
        asm volatile("" ::: "memory");
        if (kt + 2 < 8) stage(buf, (kt + 2) * 32);
    }

    const int r0 = (l >> 4) * 4;
    const int cl = l & 15;
#pragma unroll
    for (int i = 0; i < 4; ++i) {
        const int row = m0 + wr * 64 + i * 16 + r0;
#pragma unroll
        for (int j = 0; j < 4; ++j) {
            const int col = n0 + wc * 64 + j * 16 + cl;
            if (OUT_BF16) {
                __hip_bfloat16* Cp = (__hip_bfloat16*)Cv + (size_t)z * strideC;
#pragma unroll
                for (int r = 0; r < 4; ++r)
                    Cp[(size_t)(row + r) * ldc + col] = __float2bfloat16(acc[i][j][r]);
            } else {
                float* Cp = (float*)Cv + (size_t)z * strideC;
#pragma unroll
                for (int r = 0; r < 4; ++r)
                    Cp[(size_t)(row + r) * ldc + col] = acc[i][j][r];
            }
        }
    }
}

// Fused K/V GEMM, 2-phase dbuf: A staged once per K-step, two B operands,
// 32 MFMA per step. 24 chunks per stage (A x8, Bk x8, Bv x8), 6 per wave.
__global__ __launch_bounds__(256) void gemm_kv_kernel(
    const __hip_bfloat16* __restrict__ xt,   // [z][4096][256]
    const __hip_bfloat16* __restrict__ Wk,   // [256][256]
    const __hip_bfloat16* __restrict__ Wv,   // [256][256]
    __hip_bfloat16* __restrict__ Kt,         // [z][4096][256]
    __hip_bfloat16* __restrict__ Vt)         // [z][4096][256]
{
    __shared__ __align__(16) __hip_bfloat16 Alds[2][4096];
    __shared__ __align__(16) __hip_bfloat16 Bklds[2][4096];
    __shared__ __align__(16) __hip_bfloat16 Bvlds[2][4096];
    const int n0 = blockIdx.x * 128;
    const int m0 = blockIdx.y * 128;
    const int z  = blockIdx.z;
    const __hip_bfloat16* A = xt + (size_t)z * (HW * C_DIM);

    const int t  = threadIdx.x;
    const int wv = t >> 6, l = t & 63;
    const int wr = wv >> 1, wc = wv & 1;

    f32x4 acck[4][4], accv[4][4];
#pragma unroll
    for (int i = 0; i < 4; ++i)
#pragma unroll
        for (int j = 0; j < 4; ++j) {
#pragma unroll
            for (int r = 0; r < 4; ++r) { acck[i][j][r] = 0.f; accv[i][j][r] = 0.f; }
        }

    const int kb_l = l >> 4;
    const int rl   = l & 15;

    auto stage = [&](int buf, int k0) {
#pragma unroll
        for (int c2 = 0; c2 < 6; ++c2) {
            const int c      = wv * 6 + c2;       // 0..23
            const int target = c >> 3;            // 0:A 1:Bk 2:Bv
            const int sub    = c & 7;             // 0..7
            const int kb     = sub >> 1, half = sub & 1;
            const int row    = half * 64 + l;
            const __hip_bfloat16* gsrc =
                target == 0 ? (A + (size_t)(m0 + row) * 256)
                            : (target == 1 ? (Wk + (size_t)(n0 + row) * 256)
                                           : (Wv + (size_t)(n0 + row) * 256));
            __hip_bfloat16* lbase =
                (target == 0 ? &Alds[0][0] : (target == 1 ? &Bklds[0][0] : &Bvlds[0][0]));
            __builtin_amdgcn_global_load_lds(
                (const __attribute__((address_space(1))) void*)(gsrc + k0 + kb * 8),
                (__attribute__((address_space(3))) void*)(lbase + buf * 4096 + kb * 1024 + half * 512),
                16, 0, 0);
        }
    };

    stage(0, 0);
    stage(1, 32);

    for (int kt = 0; kt < 8; ++kt) {
        const int buf = kt & 1;
        if (kt < 7) asm volatile("s_waitcnt vmcnt(6)" ::: "memory");
        else        asm volatile("s_waitcnt vmcnt(0)" ::: "memory");
        __builtin_amdgcn_s_barrier();
        asm volatile("" ::: "memory");

        bf16x8 af[4], bk[4], bv[4];
#pragma unroll
        for (int i = 0; i < 4; ++i)
            af[i] = *(const bf16x8*)&Alds[buf][kb_l * 1024 + (wr * 64 + i * 16 + rl) * 8];
#pragma unroll
        for (int j = 0; j < 4; ++j) {
            bk[j] = *(const bf16x8*)&Bklds[buf][kb_l * 1024 + (wc * 64 + j * 16 + rl) * 8];
            bv[j] = *(const bf16x8*)&Bvlds[buf][kb_l * 1024 + (wc * 64 + j * 16 + rl) * 8];
        }
#pragma unroll
        for (int i = 0; i < 4; ++i)
#pragma unroll
            for (int j = 0; j < 4; ++j) {
                acck[i][j] = __builtin_amdgcn_mfma_f32_16x16x32_bf16(af[i], bk[j], acck[i][j], 0, 0, 0);
                accv[i][j] = __builtin_amdgcn_mfma_f32_16x16x32_bf16(af[i], bv[j], accv[i][j], 0, 0, 0);
            }

        asm volatile("" ::: "memory");
        __builtin_amdgcn_s_barrier();
        asm volatile("" ::: "memory");
        if (kt + 2 < 8) stage(buf, (kt + 2) * 32);
    }

    const int r0 = (l >> 4) * 4;
    const int cl = l & 15;
    __hip_bfloat16* Kp = Kt + (size_t)z * (HW * C_DIM);
    __hip_bfloat16* Vp = Vt + (size_t)z * (HW * C_DIM);
#pragma unroll
    for (int i = 0; i < 4; ++i) {
        const int row = m0 + wr * 64 + i * 16 + r0;
#pragma unroll
        for (int j = 0; j < 4; ++j) {
            const int col = n0 + wc * 64 + j * 16 + cl;
#pragma unroll
            for (int r = 0; r < 4; ++r) {
                Kp[(size_t)(row + r) * 256 + col] = __float2bfloat16(acck[i][j][r]);
                Vp[(size_t)(row + r) * 256 + col] = __float2bfloat16(accv[i][j][r]);
            }
        }
    }
}

// One thread per (b, w, h): all loads contiguous 64B per head slice.
__global__ __launch_bounds__(256) void attn_kernel(
    const __hip_bfloat16* __restrict__ Qloc,  // [nb][4096][256] bf16
    const __hip_bfloat16* __restrict__ Kt,    // [nb*6][4096][256]
    const __hip_bfloat16* __restrict__ Vt,
    __hip_bfloat16* __restrict__ outT)        // [nb][4096][256]
{
    const int t  = blockIdx.x * 256 + threadIdx.x;
    const int h  = t & 7;
    const int bw = t >> 3;                 // b*4096 + w
    const int b  = bw >> 12;
    const int w  = bw & 4095;
    const float scale = 0.17677669529663687f;  // 32^-0.5

    float q[32];
    const bf16x8* Qp = (const bf16x8*)(Qloc + (size_t)bw * C_DIM + h * 32);
#pragma unroll
    for (int i = 0; i < 4; ++i) {
        bf16x8 qv = Qp[i];
#pragma unroll
        for (int j = 0; j < 8; ++j) q[8 * i + j] = (float)qv[j];
    }

    float s[NV];
#pragma unroll
    for (int v = 0; v < NV; ++v) {
        const bf16x8* Kp = (const bf16x8*)(Kt + ((size_t)(b * NV + v) * HW + w) * C_DIM + h * 32);
        float a = 0.f;
#pragma unroll
        for (int i = 0; i < 4; ++i) {
            bf16x8 kv = Kp[i];
#pragma unroll
            for (int j = 0; j < 8; ++j) a += q[8 * i + j] * (float)kv[j];
        }
        s[v] = a * scale;
    }
    float m = s[0];
#pragma unroll
    for (int v = 1; v < NV; ++v) m = fmaxf(m, s[v]);
    float den = 0.f;
#pragma unroll
    for (int v = 0; v < NV; ++v) { s[v] = __expf(s[v] - m); den += s[v]; }
    const float inv = 1.f / den;

    float o[32];
#pragma unroll
    for (int d = 0; d < 32; ++d) o[d] = 0.f;
#pragma unroll
    for (int v = 0; v < NV; ++v) {
        const float p = s[v] * inv;
        const bf16x8* Vp = (const bf16x8*)(Vt + ((size_t)(b * NV + v) * HW + w) * C_DIM + h * 32);
#pragma unroll
        for (int i = 0; i < 4; ++i) {
            bf16x8 vv = Vp[i];
#pragma unroll
            for (int j = 0; j < 8; ++j) o[8 * i + j] += p * (float)vv[j];
        }
    }
    __hip_bfloat16* op = outT + (size_t)bw * C_DIM + h * 32;
#pragma unroll
    for (int i = 0; i < 4; ++i) {
        bf16x8 ov;
#pragma unroll
        for (int j = 0; j < 8; ++j) ov[j] = (__bf16)o[8 * i + j];
        *(bf16x8*)(op + 8 * i) = ov;
    }
}

extern "C" void kernel_launch(void* const* d_in, const int* in_sizes, int n_in,
                              void* d_out, int out_size, void* d_ws, size_t ws_size,
                              hipStream_t stream)
{
    const float* x  = (const float*)d_in[0];
    const float* Wq = (const float*)d_in[1];
    const float* Wk = (const float*)d_in[2];
    const float* Wv = (const float*)d_in[3];
    const float* Wo = (const float*)d_in[4];
    (void)in_sizes; (void)n_in; (void)out_size; (void)ws_size;

    char* ws = (char*)d_ws;
    const size_t MB = 1024ull * 1024ull;
    const size_t SL = (size_t)HW * C_DIM;                    // 1M elements per slice

    __hip_bfloat16* Wbf   = (__hip_bfloat16*)(ws);           // 512 KB
    __hip_bfloat16* xt    = (__hip_bfloat16*)(ws + 1 * MB);  // 48 MB [4*6][4096][256]
    __hip_bfloat16* Qloc  = (__hip_bfloat16*)(ws + 49 * MB); // 8 MB  [4][4096][256] bf16
    __hip_bfloat16* xbar  = (__hip_bfloat16*)(ws + 57 * MB); // 8 MB  [4][4096][256]
    __hip_bfloat16* attnT = xbar;                            // overlay: xbar dead after Qloc gemm
    __hip_bfloat16* Kt    = (__hip_bfloat16*)(ws + 65 * MB); // 48 MB
    __hip_bfloat16* Vt    = (__hip_bfloat16*)(ws + 113 * MB);// 48 MB

    const __hip_bfloat16* WqB = Wbf;
    const __hip_bfloat16* WkB = Wbf + 65536;
    const __hip_bfloat16* WvB = Wbf + 131072;
    const __hip_bfloat16* WoB = Wbf + 196608;

    convert_weights_kernel<<<dim3(256, 4), 256, 0, stream>>>(Wq, Wk, Wv, Wo, Wbf);
    transpose_mean_kernel<<<dim3(HW / 64, C_DIM / 64, NB), 256, 0, stream>>>(x, xt, xbar);

    // Qloc[b][w][c] bf16 = xbar @ Wq^T
    gemm_generic<1><<<dim3(2, 32, NB), 256, 0, stream>>>(xbar, SL, WqB, 0, Qloc, SL, 256);

    // Kt/Vt fused
    gemm_kv_kernel<<<dim3(2, 32, NB * NV), 256, 0, stream>>>(xt, WkB, WvB, Kt, Vt);

    attn_kernel<<<dim3(NB * 128), 256, 0, stream>>>(Qloc, Kt, Vt, attnT);

    // d_out[b][o][w] fp32 = Wo @ attnT
    gemm_generic<0><<<dim3(32, 2, NB), 256, 0, stream>>>(WoB, 0, attnT, SL, (float*)d_out, SL, 4096);
}